// Round 6
// baseline (300.727 us; speedup 1.0000x reference)
//
#include <hip/hip_runtime.h>
#include <hip/hip_bf16.h>

// Problem constants (match reference)
constexpr int Bq  = 4;
constexpr int Nn  = 10000;
constexpr int Eq  = 170000;
constexpr int FIN = 256;
constexpr int Ff  = 128;
constexpr int Hh  = 4;
constexpr int C   = Hh * Ff;    // 512 output cols
constexpr float LEAKY = 0.2f;

typedef short short4v __attribute__((ext_vector_type(4)));
typedef short short8  __attribute__((ext_vector_type(8)));
typedef float f32x4   __attribute__((ext_vector_type(4)));

// float -> bf16 bits, round-to-nearest-even
static __device__ __forceinline__ unsigned short f2bf(float f) {
    unsigned int u = __float_as_uint(f);
    u = u + 0x7fffu + ((u >> 16) & 1u);
    return (unsigned short)(u >> 16);
}
static __device__ __forceinline__ float bf2f(unsigned short b) {
    return __uint_as_float(((unsigned int)b) << 16);
}

// ---------- K1: Xb[n][b][k] = bf16(x[b][n][k])  +  fused projections -------
// 8 nodes/block. While converting the b=3 slice, also compute the 8 attention
// projection dots (ps/pd per head) via half-wave shuffle reduce.
__global__ __launch_bounds__(256) void xprep_proj_kernel(
    const float* __restrict__ X, const float* __restrict__ wa,
    const float* __restrict__ bsd, unsigned short* __restrict__ Xb,
    float* __restrict__ psT, float* __restrict__ pdT)
{
    int n0 = blockIdx.x * 8;
    int t  = threadIdx.x;
    int r  = t >> 5;          // 0..7 (node within block; half-wave)
    int c  = t & 31;
    int k8 = c * 8;           // 0..248
    float s[8];
    #pragma unroll
    for (int i = 0; i < 8; ++i) s[i] = 0.f;

    #pragma unroll
    for (int b = 0; b < Bq; ++b) {
        const float* p = X + ((size_t)b * Nn + n0 + r) * FIN + k8;
        float4 v0 = *(const float4*)p, v1 = *(const float4*)(p + 4);
        short8 v;
        v[0] = (short)f2bf(v0.x); v[1] = (short)f2bf(v0.y);
        v[2] = (short)f2bf(v0.z); v[3] = (short)f2bf(v0.w);
        v[4] = (short)f2bf(v1.x); v[5] = (short)f2bf(v1.y);
        v[6] = (short)f2bf(v1.z); v[7] = (short)f2bf(v1.w);
        *(short8*)(Xb + ((size_t)(n0 + r) * Bq + b) * FIN + k8) = v;
        if (b == Bq - 1) {
            #pragma unroll
            for (int i = 0; i < 8; ++i) {
                const float* w = wa + (size_t)i * FIN + k8;
                float4 w0 = *(const float4*)w, w1 = *(const float4*)(w + 4);
                s[i] = v0.x * w0.x + v0.y * w0.y + v0.z * w0.z + v0.w * w0.w
                     + v1.x * w1.x + v1.y * w1.y + v1.z * w1.z + v1.w * w1.w;
            }
        }
    }
    // reduce within half-wave (32 lanes; xor<32 never crosses bit 5)
    #pragma unroll
    for (int off = 1; off < 32; off <<= 1)
        #pragma unroll
        for (int i = 0; i < 8; ++i) s[i] += __shfl_xor(s[i], off, 64);
    if (c == 0) {
        int n = n0 + r;
        #pragma unroll
        for (int hi = 0; hi < 4; ++hi) {
            psT[n * 4 + hi] = s[hi]     + bsd[hi];
            pdT[n * 4 + hi] = s[4 + hi] + bsd[4 + hi];
        }
    }
}

// ---------- K2: Wf in MFMA B-fragment order --------------------------------
// unit u = ((hi*8 + j)*8 + ks)*64 + quad*16 + ln holds
// B[k = ks*32 + quad*8 + el][col = hi*128 + j*16 + ln], el = 0..7.
__global__ void wprep_kernel(const float* __restrict__ W, unsigned short* __restrict__ Wf)
{
    int cc = blockIdx.x;  // 0..511 (col = hi*128 + f)
    int k = threadIdx.x;  // 0..255
    float v = W[(size_t)(cc >> 7) * FIN * Ff + (size_t)k * Ff + (cc & 127)];
    int w = cc >> 7, j = (cc >> 4) & 7, ln = cc & 15;
    int ks = k >> 5, quad = (k >> 3) & 3, el = k & 7;
    size_t u = ((size_t)((w * 8 + j) * 8 + ks) * 4 + quad) * 16 + ln;
    Wf[u * 8 + el] = f2bf(v);
}

// ---------- K3: wa[v][hi][k] = sum_f W[hi][k][f]*a_v[hi][f]; bsd[v][hi] ----
__global__ __launch_bounds__(256) void waprep_kernel(
    const float* __restrict__ W, const float* __restrict__ Wattn,
    const float* __restrict__ bmlp, float* __restrict__ wa, float* __restrict__ bsd)
{
    int t = threadIdx.x;
    int hi = t >> 6, kb = t & 63;
    #pragma unroll
    for (int i = 0; i < 4; ++i) {
        int k = kb + i * 64;
        float ss = 0.f, sd = 0.f;
        const float* wrow = W + ((size_t)hi * FIN + k) * Ff;
        const float* as = Wattn + hi * 2 * Ff;
        const float* ad = as + Ff;
        for (int f = 0; f < Ff; f += 4) {
            float4 wv = *(const float4*)(wrow + f);
            float4 av = *(const float4*)(as + f);
            float4 dv = *(const float4*)(ad + f);
            ss += wv.x * av.x + wv.y * av.y + wv.z * av.z + wv.w * av.w;
            sd += wv.x * dv.x + wv.y * dv.y + wv.z * dv.z + wv.w * dv.w;
        }
        wa[(0 * 4 + hi) * FIN + k] = ss;
        wa[(1 * 4 + hi) * FIN + k] = sd;
    }
    if (t < 8) {
        int v = t & 1, hh = t >> 1;
        float s = 0.f;
        for (int f = 0; f < Ff; ++f)
            s += bmlp[hh * Ff + f] * Wattn[hh * 2 * Ff + v * Ff + f];
        bsd[v * 4 + hh] = s;
    }
}

// ---------- K4: row_start via binary search (src sorted) -------------------
__global__ void row_start_kernel(const int* __restrict__ src, int* __restrict__ row_start)
{
    int n = blockIdx.x * blockDim.x + threadIdx.x;
    if (n > Nn) return;
    int lo = 0, hi = Eq;
    while (lo < hi) { int mid = (lo + hi) >> 1; if (src[mid] < n) lo = mid + 1; else hi = mid; }
    row_start[n] = lo;
}

// ---------- K5: fused edge scores + denom (wave per node, 4 nodes/block) ---
__global__ __launch_bounds__(256) void edge_denom_kernel(
    const int* __restrict__ dst, const int* __restrict__ row_start,
    const float* __restrict__ psT, const float* __restrict__ pdT,
    float* __restrict__ eed, float* __restrict__ denom)
{
    int wv = threadIdx.x >> 6, t = threadIdx.x & 63;
    int n = blockIdx.x * 4 + wv;
    int e0 = row_start[n], e1 = row_start[n + 1];
    float4 ps = *(const float4*)(psT + (size_t)n * 4);
    float4 acc = {0.f, 0.f, 0.f, 0.f};
    for (int e = e0 + t; e < e1; e += 64) {
        int d = dst[e];
        float4 pd = *(const float4*)(pdT + (size_t)d * 4);
        float4 ev;
        { float sc = ps.x + pd.x; float lr = sc > 0.f ? sc : LEAKY * sc;
          ev.x = __expf(fminf(fmaxf(lr, -2.f), 2.f)); }
        { float sc = ps.y + pd.y; float lr = sc > 0.f ? sc : LEAKY * sc;
          ev.y = __expf(fminf(fmaxf(lr, -2.f), 2.f)); }
        { float sc = ps.z + pd.z; float lr = sc > 0.f ? sc : LEAKY * sc;
          ev.z = __expf(fminf(fmaxf(lr, -2.f), 2.f)); }
        { float sc = ps.w + pd.w; float lr = sc > 0.f ? sc : LEAKY * sc;
          ev.w = __expf(fminf(fmaxf(lr, -2.f), 2.f)); }
        *(float4*)(eed + (size_t)e * 4) = ev;
        acc.x += ev.x; acc.y += ev.y; acc.z += ev.z; acc.w += ev.w;
    }
    #pragma unroll
    for (int off = 32; off; off >>= 1) {
        acc.x += __shfl_down(acc.x, off, 64);
        acc.y += __shfl_down(acc.y, off, 64);
        acc.z += __shfl_down(acc.z, off, 64);
        acc.w += __shfl_down(acc.w, off, 64);
    }
    if (t == 0) *(float4*)(denom + (size_t)n * 4) = acc;
}

// ---------- K6: fused gather + per-head GEMM -------------------------------
// Block per 8 nodes. Phase 1: per node, gather gx rows (4hi x 4b x 256k) into
// registers (thread: b=t>>6, k0=(t&63)*4), dump bf16 to padded LDS tile.
// Phase 2: wave w = head w; MFMA M=32(8n x 4b) x K=256 x N=128; direct fp32
// stores to out with denom!=0 bias guard.
__global__ __launch_bounds__(256) void gather_gemm_kernel(
    const unsigned short* __restrict__ Xb, const float* __restrict__ eed,
    const float* __restrict__ denom, const int* __restrict__ row_start,
    const int* __restrict__ dst, const unsigned short* __restrict__ Wf,
    const float* __restrict__ bias, float* __restrict__ out)
{
    __shared__ unsigned short gx[4][32][264]; // 66 KB, 528B row stride (4-bank rot)

    const int n0 = blockIdx.x * 8;
    const int t  = threadIdx.x;
    const int b  = t >> 6;
    const int k0 = (t & 63) * 4;
    const float4* eed4 = (const float4*)eed;

    for (int ni = 0; ni < 8; ++ni) {
        int n = n0 + ni;
        int e0 = row_start[n], e1 = row_start[n + 1];
        float4 dn = *(const float4*)(denom + (size_t)n * 4);
        float inv0 = dn.x != 0.f ? 1.f / dn.x : 0.f;
        float inv1 = dn.y != 0.f ? 1.f / dn.y : 0.f;
        float inv2 = dn.z != 0.f ? 1.f / dn.z : 0.f;
        float inv3 = dn.w != 0.f ? 1.f / dn.w : 0.f;

        float acc[4][4];
        #pragma unroll
        for (int hi = 0; hi < 4; ++hi)
            #pragma unroll
            for (int j = 0; j < 4; ++j) acc[hi][j] = 0.f;

        size_t boff = (size_t)b * FIN + k0;
        int e = e0;
        for (; e + 4 <= e1; e += 4) {
            int d0 = dst[e], d1 = dst[e + 1], d2 = dst[e + 2], d3 = dst[e + 3];
            short4v v0 = *(const short4v*)(Xb + (size_t)d0 * 1024 + boff);
            short4v v1 = *(const short4v*)(Xb + (size_t)d1 * 1024 + boff);
            short4v v2 = *(const short4v*)(Xb + (size_t)d2 * 1024 + boff);
            short4v v3 = *(const short4v*)(Xb + (size_t)d3 * 1024 + boff);
            float4 ev0 = eed4[e], ev1 = eed4[e + 1], ev2 = eed4[e + 2], ev3 = eed4[e + 3];
            float w[4][4] = {
                {ev0.x * inv0, ev0.y * inv1, ev0.z * inv2, ev0.w * inv3},
                {ev1.x * inv0, ev1.y * inv1, ev1.z * inv2, ev1.w * inv3},
                {ev2.x * inv0, ev2.y * inv1, ev2.z * inv2, ev2.w * inv3},
                {ev3.x * inv0, ev3.y * inv1, ev3.z * inv2, ev3.w * inv3}};
            #pragma unroll
            for (int j = 0; j < 4; ++j) {
                float f0 = bf2f((unsigned short)v0[j]);
                float f1 = bf2f((unsigned short)v1[j]);
                float f2 = bf2f((unsigned short)v2[j]);
                float f3 = bf2f((unsigned short)v3[j]);
                #pragma unroll
                for (int hi = 0; hi < 4; ++hi)
                    acc[hi][j] += f0 * w[0][hi] + f1 * w[1][hi] + f2 * w[2][hi] + f3 * w[3][hi];
            }
        }
        for (; e < e1; ++e) {
            int d0 = dst[e];
            short4v v0 = *(const short4v*)(Xb + (size_t)d0 * 1024 + boff);
            float4 ev0 = eed4[e];
            float w0 = ev0.x * inv0, w1 = ev0.y * inv1, w2 = ev0.z * inv2, w3 = ev0.w * inv3;
            #pragma unroll
            for (int j = 0; j < 4; ++j) {
                float f = bf2f((unsigned short)v0[j]);
                acc[0][j] += f * w0; acc[1][j] += f * w1;
                acc[2][j] += f * w2; acc[3][j] += f * w3;
            }
        }

        int row = ni * 4 + b;
        #pragma unroll
        for (int hi = 0; hi < 4; ++hi) {
            short4v o;
            #pragma unroll
            for (int j = 0; j < 4; ++j) o[j] = (short)f2bf(acc[hi][j]);
            *(short4v*)&gx[hi][row][k0] = o;
        }
    }
    __syncthreads();

    // ---- MFMA phase: wave = head ----
    const int wave = t >> 6, lane = t & 63;
    const int quad = lane >> 4, ln = lane & 15;
    const int hi = wave;

    f32x4 macc[2][8];
    #pragma unroll
    for (int i = 0; i < 2; ++i)
        #pragma unroll
        for (int j = 0; j < 8; ++j) macc[i][j] = (f32x4){0.f, 0.f, 0.f, 0.f};

    const short8* Wf8 = (const short8*)Wf;
    #pragma unroll
    for (int ks = 0; ks < 8; ++ks) {
        short8 a0 = *(const short8*)&gx[hi][ln][ks * 32 + quad * 8];
        short8 a1 = *(const short8*)&gx[hi][16 + ln][ks * 32 + quad * 8];
        #pragma unroll
        for (int j = 0; j < 8; ++j) {
            short8 bf = Wf8[(size_t)((hi * 8 + j) * 8 + ks) * 64 + lane];
            macc[0][j] = __builtin_amdgcn_mfma_f32_16x16x32_bf16(a0, bf, macc[0][j], 0, 0, 0);
            macc[1][j] = __builtin_amdgcn_mfma_f32_16x16x32_bf16(a1, bf, macc[1][j], 0, 0, 0);
        }
    }

    #pragma unroll
    for (int j = 0; j < 8; ++j) {
        int colf = j * 16 + ln;                 // col within head, 0..127
        float bv = bias[hi * Ff + colf];
        #pragma unroll
        for (int mt = 0; mt < 2; ++mt) {
            #pragma unroll
            for (int r = 0; r < 4; ++r) {
                int m = mt * 16 + quad * 4 + r;
                int nn = n0 + (m >> 2), bb = m & 3;
                float flag = denom[(size_t)nn * 4 + hi] != 0.f ? 1.f : 0.f;
                out[((size_t)bb * Nn + nn) * C + hi * Ff + colf] = macc[mt][j][r] + bv * flag;
            }
        }
    }
}

// -------------------- launch --------------------
extern "C" void kernel_launch(void* const* d_in, const int* in_sizes, int n_in,
                              void* d_out, int out_size, void* d_ws, size_t ws_size,
                              hipStream_t stream)
{
    const float* x      = (const float*)d_in[0]; // (B,N,256)
    const float* W_mlp  = (const float*)d_in[1]; // (H,256,128)
    const float* b_mlp  = (const float*)d_in[2]; // (H,128)
    const float* W_attn = (const float*)d_in[3]; // (H,256,1)
    const int*   src    = (const int*)d_in[4];   // (E,)
    const int*   dst    = (const int*)d_in[5];   // (E,)
    float* out = (float*)d_out;                  // (B,N,512)

    // workspace layout
    unsigned short* Xb  = (unsigned short*)d_ws;          // 10000*4*256 bf16 = 20.48 MB
    unsigned short* Wf  = Xb + (size_t)Nn * Bq * FIN;     // 512*256 bf16
    float* eed   = (float*)(Wf + (size_t)C * FIN);        // E*4 floats
    float* psT   = eed + (size_t)Eq * 4;                  // N*4
    float* pdT   = psT + (size_t)Nn * 4;                  // N*4
    float* denom = pdT + (size_t)Nn * 4;                  // N*4
    float* wa    = denom + (size_t)Nn * 4;                // 2*4*256
    float* bsd   = wa + 2 * 4 * FIN;                      // 8 (pad 16)
    int*   row_st = (int*)(bsd + 16);                     // N+1

    hipLaunchKernelGGL(wprep_kernel, dim3(C), dim3(FIN), 0, stream, W_mlp, Wf);
    hipLaunchKernelGGL(waprep_kernel, dim3(1), dim3(256), 0, stream,
                       W_mlp, W_attn, b_mlp, wa, bsd);
    hipLaunchKernelGGL(row_start_kernel, dim3((Nn + 256) / 256), dim3(256), 0, stream,
                       src, row_st);
    hipLaunchKernelGGL(xprep_proj_kernel, dim3(Nn / 8), dim3(256), 0, stream,
                       x, wa, bsd, Xb, psT, pdT);
    hipLaunchKernelGGL(edge_denom_kernel, dim3(Nn / 4), dim3(256), 0, stream,
                       dst, row_st, psT, pdT, eed, denom);
    hipLaunchKernelGGL(gather_gemm_kernel, dim3(Nn / 8), dim3(256), 0, stream,
                       Xb, eed, denom, row_st, dst, Wf, b_mlp, out);
}

// Round 7
// 231.188 us; speedup vs baseline: 1.3008x; 1.3008x over previous
//
#include <hip/hip_runtime.h>
#include <hip/hip_bf16.h>

// Problem constants (match reference)
constexpr int Bq  = 4;
constexpr int Nn  = 10000;
constexpr int Eq  = 170000;
constexpr int FIN = 256;
constexpr int Ff  = 128;
constexpr int Hh  = 4;
constexpr int Mrows = Nn * Bq;  // per-head GEMM2 M = 40000 (n*4+b)
constexpr int C   = Hh * Ff;    // 512 output cols
constexpr float LEAKY = 0.2f;

typedef short short4v __attribute__((ext_vector_type(4)));
typedef short short8  __attribute__((ext_vector_type(8)));
typedef float f32x4   __attribute__((ext_vector_type(4)));

// float -> bf16 bits, round-to-nearest-even
static __device__ __forceinline__ unsigned short f2bf(float f) {
    unsigned int u = __float_as_uint(f);
    u = u + 0x7fffu + ((u >> 16) & 1u);
    return (unsigned short)(u >> 16);
}
static __device__ __forceinline__ float bf2f(unsigned short b) {
    return __uint_as_float(((unsigned int)b) << 16);
}

// ---------- K1: prep — Wf fragment layout, wa/bsd, row_start (one launch) --
// blocks 0..511: Wf; block 512: wa+bsd; blocks 513..552: row_start.
__global__ __launch_bounds__(256) void prep_kernel(
    const float* __restrict__ W, const float* __restrict__ Wattn,
    const float* __restrict__ bmlp, const int* __restrict__ src,
    unsigned short* __restrict__ Wf, float* __restrict__ wa,
    float* __restrict__ bsd, int* __restrict__ row_start)
{
    int bid = blockIdx.x, t = threadIdx.x;
    if (bid < 512) {
        // Wf unit u = ((hi*8 + j)*8 + ks)*64 + quad*16 + ln holds
        // B[k = ks*32 + quad*8 + el][col = hi*128 + j*16 + ln], el = 0..7.
        int cc = bid;  // col = hi*128 + f
        int k = t;
        float v = W[(size_t)(cc >> 7) * FIN * Ff + (size_t)k * Ff + (cc & 127)];
        int w = cc >> 7, j = (cc >> 4) & 7, ln = cc & 15;
        int ks = k >> 5, quad = (k >> 3) & 3, el = k & 7;
        size_t u = ((size_t)((w * 8 + j) * 8 + ks) * 4 + quad) * 16 + ln;
        Wf[u * 8 + el] = f2bf(v);
    } else if (bid == 512) {
        // wa[v][hi][k] = sum_f W[hi][k][f]*a_v[hi][f]; bsd[v][hi] = b.a_v
        int hi = t >> 6, kb = t & 63;
        #pragma unroll
        for (int i = 0; i < 4; ++i) {
            int k = kb + i * 64;
            float ss = 0.f, sd = 0.f;
            const float* wrow = W + ((size_t)hi * FIN + k) * Ff;
            const float* as = Wattn + hi * 2 * Ff;
            const float* ad = as + Ff;
            for (int f = 0; f < Ff; f += 4) {
                float4 wv = *(const float4*)(wrow + f);
                float4 av = *(const float4*)(as + f);
                float4 dv = *(const float4*)(ad + f);
                ss += wv.x * av.x + wv.y * av.y + wv.z * av.z + wv.w * av.w;
                sd += wv.x * dv.x + wv.y * dv.y + wv.z * dv.z + wv.w * dv.w;
            }
            wa[(0 * 4 + hi) * FIN + k] = ss;
            wa[(1 * 4 + hi) * FIN + k] = sd;
        }
        if (t < 8) {
            int v = t & 1, hh = t >> 1;
            float s = 0.f;
            for (int f = 0; f < Ff; ++f)
                s += bmlp[hh * Ff + f] * Wattn[hh * 2 * Ff + v * Ff + f];
            bsd[v * 4 + hh] = s;
        }
    } else {
        int n = (bid - 513) * 256 + t;
        if (n > Nn) return;
        int lo = 0, hi = Eq;
        while (lo < hi) { int mid = (lo + hi) >> 1; if (src[mid] < n) lo = mid + 1; else hi = mid; }
        row_start[n] = lo;
    }
}

// ---------- K2: Xb[n][b][k] = bf16(x[b][n][k]) + fused projections ---------
__global__ __launch_bounds__(256) void xprep_proj_kernel(
    const float* __restrict__ X, const float* __restrict__ wa,
    const float* __restrict__ bsd, unsigned short* __restrict__ Xb,
    float* __restrict__ psT, float* __restrict__ pdT)
{
    int n0 = blockIdx.x * 8;
    int t  = threadIdx.x;
    int r  = t >> 5;          // 0..7 (node within block; half-wave)
    int c  = t & 31;
    int k8 = c * 8;           // 0..248
    float s[8];
    #pragma unroll
    for (int i = 0; i < 8; ++i) s[i] = 0.f;

    #pragma unroll
    for (int b = 0; b < Bq; ++b) {
        const float* p = X + ((size_t)b * Nn + n0 + r) * FIN + k8;
        float4 v0 = *(const float4*)p, v1 = *(const float4*)(p + 4);
        short8 v;
        v[0] = (short)f2bf(v0.x); v[1] = (short)f2bf(v0.y);
        v[2] = (short)f2bf(v0.z); v[3] = (short)f2bf(v0.w);
        v[4] = (short)f2bf(v1.x); v[5] = (short)f2bf(v1.y);
        v[6] = (short)f2bf(v1.z); v[7] = (short)f2bf(v1.w);
        *(short8*)(Xb + ((size_t)(n0 + r) * Bq + b) * FIN + k8) = v;
        if (b == Bq - 1) {
            #pragma unroll
            for (int i = 0; i < 8; ++i) {
                const float* w = wa + (size_t)i * FIN + k8;
                float4 w0 = *(const float4*)w, w1 = *(const float4*)(w + 4);
                s[i] = v0.x * w0.x + v0.y * w0.y + v0.z * w0.z + v0.w * w0.w
                     + v1.x * w1.x + v1.y * w1.y + v1.z * w1.z + v1.w * w1.w;
            }
        }
    }
    #pragma unroll
    for (int off = 1; off < 32; off <<= 1)
        #pragma unroll
        for (int i = 0; i < 8; ++i) s[i] += __shfl_xor(s[i], off, 64);
    if (c == 0) {
        int n = n0 + r;
        #pragma unroll
        for (int hi = 0; hi < 4; ++hi) {
            psT[n * 4 + hi] = s[hi]     + bsd[hi];
            pdT[n * 4 + hi] = s[4 + hi] + bsd[4 + hi];
        }
    }
}

// ---------- K3: edge scores -> PRE-NORMALIZED weights + denom --------------
// Wave per node (4/block). Pass 1: compute e, store, butterfly-reduce sum.
// Pass 2: scale stored e by 1/denom in place. denom kept for bias flag.
__global__ __launch_bounds__(256) void edge_denom_kernel(
    const int* __restrict__ dst, const int* __restrict__ row_start,
    const float* __restrict__ psT, const float* __restrict__ pdT,
    float* __restrict__ eed, float* __restrict__ denom)
{
    int wv = threadIdx.x >> 6, t = threadIdx.x & 63;
    int n = blockIdx.x * 4 + wv;
    int e0 = row_start[n], e1 = row_start[n + 1];
    float4 ps = *(const float4*)(psT + (size_t)n * 4);
    float4 acc = {0.f, 0.f, 0.f, 0.f};
    for (int e = e0 + t; e < e1; e += 64) {
        int d = dst[e];
        float4 pd = *(const float4*)(pdT + (size_t)d * 4);
        float4 ev;
        { float sc = ps.x + pd.x; float lr = sc > 0.f ? sc : LEAKY * sc;
          ev.x = __expf(fminf(fmaxf(lr, -2.f), 2.f)); }
        { float sc = ps.y + pd.y; float lr = sc > 0.f ? sc : LEAKY * sc;
          ev.y = __expf(fminf(fmaxf(lr, -2.f), 2.f)); }
        { float sc = ps.z + pd.z; float lr = sc > 0.f ? sc : LEAKY * sc;
          ev.z = __expf(fminf(fmaxf(lr, -2.f), 2.f)); }
        { float sc = ps.w + pd.w; float lr = sc > 0.f ? sc : LEAKY * sc;
          ev.w = __expf(fminf(fmaxf(lr, -2.f), 2.f)); }
        *(float4*)(eed + (size_t)e * 4) = ev;
        acc.x += ev.x; acc.y += ev.y; acc.z += ev.z; acc.w += ev.w;
    }
    #pragma unroll
    for (int off = 1; off < 64; off <<= 1) {
        acc.x += __shfl_xor(acc.x, off, 64);
        acc.y += __shfl_xor(acc.y, off, 64);
        acc.z += __shfl_xor(acc.z, off, 64);
        acc.w += __shfl_xor(acc.w, off, 64);
    }
    if (t == 0) *(float4*)(denom + (size_t)n * 4) = acc;
    float4 inv;
    inv.x = acc.x != 0.f ? 1.f / acc.x : 0.f;
    inv.y = acc.y != 0.f ? 1.f / acc.y : 0.f;
    inv.z = acc.z != 0.f ? 1.f / acc.z : 0.f;
    inv.w = acc.w != 0.f ? 1.f / acc.w : 0.f;
    for (int e = e0 + t; e < e1; e += 64) {
        float4 ev = *(const float4*)(eed + (size_t)e * 4);
        ev.x *= inv.x; ev.y *= inv.y; ev.z *= inv.z; ev.w *= inv.w;
        *(float4*)(eed + (size_t)e * 4) = ev;
    }
}

// ---------- K4: gather Gx[hi][n*4+b][k] = sum_e norm[hi,e]*x[b,dst_e,k] ----
// r5 structure: block per node, 10000 blocks, zero LDS, max occupancy.
// Thread t: b = t>>6, k0 = (t&63)*4; acc[hi][0..3]; 4-edge unroll.
__global__ __launch_bounds__(256) void gather_kernel(
    const unsigned short* __restrict__ Xb, const float* __restrict__ eed,
    const int* __restrict__ row_start, const int* __restrict__ dst,
    unsigned short* __restrict__ Gx)
{
    int n = blockIdx.x, t = threadIdx.x;
    int e0 = row_start[n], e1 = row_start[n + 1];

    float acc[4][4];
    #pragma unroll
    for (int hi = 0; hi < 4; ++hi)
        #pragma unroll
        for (int j = 0; j < 4; ++j) acc[hi][j] = 0.f;

    const float4* eed4 = (const float4*)eed;
    int off = t * 4;

    int e = e0;
    for (; e + 4 <= e1; e += 4) {
        int d0 = dst[e], d1 = dst[e + 1], d2 = dst[e + 2], d3 = dst[e + 3];
        short4v v0 = *(const short4v*)(Xb + (size_t)d0 * 1024 + off);
        short4v v1 = *(const short4v*)(Xb + (size_t)d1 * 1024 + off);
        short4v v2 = *(const short4v*)(Xb + (size_t)d2 * 1024 + off);
        short4v v3 = *(const short4v*)(Xb + (size_t)d3 * 1024 + off);
        float4 ev0 = eed4[e], ev1 = eed4[e + 1], ev2 = eed4[e + 2], ev3 = eed4[e + 3];
        float w[4][4] = {
            {ev0.x, ev0.y, ev0.z, ev0.w},
            {ev1.x, ev1.y, ev1.z, ev1.w},
            {ev2.x, ev2.y, ev2.z, ev2.w},
            {ev3.x, ev3.y, ev3.z, ev3.w}};
        #pragma unroll
        for (int j = 0; j < 4; ++j) {
            float f0 = bf2f((unsigned short)v0[j]);
            float f1 = bf2f((unsigned short)v1[j]);
            float f2 = bf2f((unsigned short)v2[j]);
            float f3 = bf2f((unsigned short)v3[j]);
            #pragma unroll
            for (int hi = 0; hi < 4; ++hi)
                acc[hi][j] += f0 * w[0][hi] + f1 * w[1][hi] + f2 * w[2][hi] + f3 * w[3][hi];
        }
    }
    for (; e < e1; ++e) {
        int d0 = dst[e];
        short4v v0 = *(const short4v*)(Xb + (size_t)d0 * 1024 + off);
        float4 ev0 = eed4[e];
        #pragma unroll
        for (int j = 0; j < 4; ++j) {
            float f = bf2f((unsigned short)v0[j]);
            acc[0][j] += f * ev0.x; acc[1][j] += f * ev0.y;
            acc[2][j] += f * ev0.z; acc[3][j] += f * ev0.w;
        }
    }

    int b = t >> 6, k0 = (t & 63) * 4;
    #pragma unroll
    for (int hi = 0; hi < 4; ++hi) {
        short4v o;
        #pragma unroll
        for (int j = 0; j < 4; ++j) o[j] = (short)f2bf(acc[hi][j]);
        *(short4v*)(Gx + ((size_t)hi * Mrows + (size_t)n * 4 + b) * FIN + k0) = o;
    }
}

// ---------- K5: out = Gx @ W[hi] + bias*(denom!=0), per head, 64-row -------
// grid (625, 4). Wave w -> rows [w*16, w*16+16), all 128 cols of head hi.
__global__ __launch_bounds__(256) void gemm2_kernel(
    const unsigned short* __restrict__ Gx, const unsigned short* __restrict__ Wf,
    const float* __restrict__ bias, const float* __restrict__ denom,
    float* __restrict__ out)
{
    __shared__ unsigned short As[64][264]; // 33.8 KB

    const int hi = blockIdx.y;
    const int r0 = blockIdx.x * 64;
    const int tid = threadIdx.x;
    const int wave = tid >> 6, lane = tid & 63;
    const int quad = lane >> 4, ln = lane & 15;

    const unsigned short* Arows = Gx + ((size_t)hi * Mrows + r0) * FIN;
    #pragma unroll
    for (int i = 0; i < 8; ++i) {
        int u = tid + i * 256;      // 2048 units of 8 shorts
        int row = u >> 5, cu = u & 31;
        *(short8*)&As[row][cu * 8] = *(const short8*)(Arows + (size_t)row * FIN + cu * 8);
    }
    __syncthreads();

    f32x4 macc[8];
    #pragma unroll
    for (int j = 0; j < 8; ++j) macc[j] = (f32x4){0.f, 0.f, 0.f, 0.f};

    const short8* Wf8 = (const short8*)Wf;
    const int m0 = wave * 16;
    #pragma unroll
    for (int ks = 0; ks < 8; ++ks) {
        short8 a = *(const short8*)&As[m0 + ln][ks * 32 + quad * 8];
        #pragma unroll
        for (int j = 0; j < 8; ++j) {
            short8 bf = Wf8[(size_t)((hi * 8 + j) * 8 + ks) * 64 + lane];
            macc[j] = __builtin_amdgcn_mfma_f32_16x16x32_bf16(a, bf, macc[j], 0, 0, 0);
        }
    }

    // epilogue: direct stores; bias guarded by denom!=0 (empty segments)
    #pragma unroll
    for (int j = 0; j < 8; ++j) {
        int colf = j * 16 + ln;     // col within head, 0..127
        float bv = bias[hi * Ff + colf];
        #pragma unroll
        for (int r = 0; r < 4; ++r) {
            int m = m0 + quad * 4 + r;
            int g = r0 + m;
            int nn = g >> 2, bb = g & 3;
            float flag = denom[(size_t)nn * 4 + hi] != 0.f ? 1.f : 0.f;
            out[((size_t)bb * Nn + nn) * C + hi * Ff + colf] = macc[j][r] + bv * flag;
        }
    }
}

// -------------------- launch --------------------
extern "C" void kernel_launch(void* const* d_in, const int* in_sizes, int n_in,
                              void* d_out, int out_size, void* d_ws, size_t ws_size,
                              hipStream_t stream)
{
    const float* x      = (const float*)d_in[0]; // (B,N,256)
    const float* W_mlp  = (const float*)d_in[1]; // (H,256,128)
    const float* b_mlp  = (const float*)d_in[2]; // (H,128)
    const float* W_attn = (const float*)d_in[3]; // (H,256,1)
    const int*   src    = (const int*)d_in[4];   // (E,)
    const int*   dst    = (const int*)d_in[5];   // (E,)
    float* out = (float*)d_out;                  // (B,N,512)

    // workspace layout
    unsigned short* Xb  = (unsigned short*)d_ws;          // 10000*4*256 bf16 = 20.48 MB
    unsigned short* Wf  = Xb + (size_t)Nn * Bq * FIN;     // 512*256 bf16
    unsigned short* Gx  = Wf + (size_t)C * FIN;           // 4*40000*256 bf16 = 81.92 MB
    float* eed   = (float*)(Gx + (size_t)Hh * Mrows * FIN); // E*4 floats
    float* psT   = eed + (size_t)Eq * 4;                  // N*4
    float* pdT   = psT + (size_t)Nn * 4;                  // N*4
    float* denom = pdT + (size_t)Nn * 4;                  // N*4
    float* wa    = denom + (size_t)Nn * 4;                // 2*4*256
    float* bsd   = wa + 2 * 4 * FIN;                      // 8 (pad 16)
    int*   row_st = (int*)(bsd + 16);                     // N+1

    hipLaunchKernelGGL(prep_kernel, dim3(553), dim3(256), 0, stream,
                       W_mlp, W_attn, b_mlp, src, Wf, wa, bsd, row_st);
    hipLaunchKernelGGL(xprep_proj_kernel, dim3(Nn / 8), dim3(256), 0, stream,
                       x, wa, bsd, Xb, psT, pdT);
    hipLaunchKernelGGL(edge_denom_kernel, dim3(Nn / 4), dim3(256), 0, stream,
                       dst, row_st, psT, pdT, eed, denom);
    hipLaunchKernelGGL(gather_kernel, dim3(Nn), dim3(256), 0, stream,
                       Xb, eed, row_st, dst, Gx);
    hipLaunchKernelGGL(gemm2_kernel, dim3(Mrows / 64, Hh), dim3(256), 0, stream,
                       Gx, Wf, b_mlp, denom, out);
}